// Round 9
// baseline (150.279 us; speedup 1.0000x reference)
//
#include <hip/hip_runtime.h>
#include <hip/hip_bf16.h>

typedef unsigned int u32;

// Problem constants (from reference)
#define N_NODE 8192
#define H1 512
#define R_EMB 128
#define N_EDGE 262144
#define N_REG 2048

// ---------------- workspace layout (bytes) ----------------
#define OFF_DEG        (0)               // int32 x 8192
#define OFF_ROWSTART   (64 * 1024)       // int32 x 8193
#define OFF_CURSOR     (128 * 1024)      // int32 x 8192
#define OFF_DIS        (160 * 1024)      // f32   x 8192
#define OFF_SORTED     (256 * 1024)      // int32 x 262144 (1 MiB)
#define OFF_W1S        (2 * 1024 * 1024)   // bf16 pairs: u32[8192][256] (8 MiB)  W1s = dis[s]*W1[s]
#define OFF_H1S        (10 * 1024 * 1024)  // bf16 pairs: u32[8192][256] (8 MiB)  h1s = dis[d]*relu(...)
#define OFF_W2T        (18 * 1024 * 1024)  // bf16 pairs: u32[128][256]  (128 KiB) W2 transposed
#define OFF_G          (19 * 1024 * 1024)  // bf16 pairs: u32[2048][256] (2 MiB)

__device__ inline u32 rne_bf16(float f) {
    u32 u = __float_as_uint(f);
    u += 0x7fffu + ((u >> 16) & 1u);
    return u >> 16;
}
__device__ inline float bf_lo(u32 u) { return __uint_as_float(u << 16); }
__device__ inline float bf_hi(u32 u) { return __uint_as_float(u & 0xffff0000u); }

using frag_ab = __attribute__((ext_vector_type(8))) short;  // 8 bf16 (4 VGPRs)
using frag_cd = __attribute__((ext_vector_type(4))) float;  // 4 fp32

// NOTE: parameter must NOT be named 'w' (collides with the .w member under token substitution)
#define ACC8(v, q) \
    v##0 += bf_lo(q.x); v##1 += bf_hi(q.x); \
    v##2 += bf_lo(q.y); v##3 += bf_hi(q.y); \
    v##4 += bf_lo(q.z); v##5 += bf_hi(q.z); \
    v##6 += bf_lo(q.w); v##7 += bf_hi(q.w);

__global__ void hist_kernel(const int* __restrict__ edge, int* __restrict__ deg) {
    int e = blockIdx.x * blockDim.x + threadIdx.x;
    if (e < N_EDGE) {
        int dst = edge[2 * e + 1];
        atomicAdd(&deg[dst], 1);
    }
}

// 1024 threads: exclusive scan of deg[8192] -> row_start, cursor; dis = rsqrt(deg+1).
__global__ void scan_kernel(const int* __restrict__ deg, int* __restrict__ row_start,
                            int* __restrict__ cursor, float* __restrict__ dis) {
    __shared__ int wtot[16];
    __shared__ int wpre[16];
    int t = threadIdx.x;
    int lane = t & 63;
    int wv = t >> 6;
    int base = t * 8;
    int local[8];
    int sum = 0;
#pragma unroll
    for (int j = 0; j < 8; j++) {
        local[j] = deg[base + j];
        sum += local[j];
    }
    int sc = sum;
#pragma unroll
    for (int off = 1; off < 64; off <<= 1) {
        int y = __shfl_up(sc, off, 64);
        if (lane >= off) sc += y;
    }
    if (lane == 63) wtot[wv] = sc;
    __syncthreads();
    if (wv == 0 && lane < 16) {
        int v = wtot[lane];
        int s2 = v;
#pragma unroll
        for (int off = 1; off < 16; off <<= 1) {
            int y = __shfl_up(s2, off, 64);
            if (lane >= off) s2 += y;
        }
        wpre[lane] = s2 - v;  // exclusive wave prefix
    }
    __syncthreads();
    int run = wpre[wv] + (sc - sum);
#pragma unroll
    for (int j = 0; j < 8; j++) {
        row_start[base + j] = run;
        cursor[base + j] = run;
        dis[base + j] = rsqrtf((float)(local[j] + 1));
        run += local[j];
    }
    if (t == 1023) row_start[N_NODE] = run;
}

// Fused: [0,1024) fill CSR, [1024,9216) convert W1 -> bf16*dis, [9216,9344) W2^T -> bf16.
__global__ void prep_kernel(const int* __restrict__ edge, int* __restrict__ cursor,
                            int* __restrict__ sorted_src,
                            const float* __restrict__ W1, const float* __restrict__ dis,
                            u32* __restrict__ W1s,
                            const float* __restrict__ W2, u32* __restrict__ w2t) {
    int bid = blockIdx.x;
    if (bid < 1024) {
        int e = bid * 256 + threadIdx.x;
        int src = edge[2 * e + 0];
        int dst = edge[2 * e + 1];
        int pos = atomicAdd(&cursor[dst], 1);
        sorted_src[pos] = src;
    } else if (bid < 1024 + 8192) {
        int idx = (bid - 1024) * 256 + threadIdx.x;  // 0 .. 2M-1
        int row = idx >> 8;
        int pc = idx & 255;
        float d = dis[row];
        float2 f = *(const float2*)(W1 + ((size_t)row << 9) + (pc << 1));
        W1s[idx] = rne_bf16(f.x * d) | (rne_bf16(f.y * d) << 16);
    } else {
        int idx = (bid - 9216) * 256 + threadIdx.x;  // 0..32767
        int j = idx >> 8;     // output column
        int p = idx & 255;    // k-pair
        float a = W2[(size_t)(2 * p) * R_EMB + j];
        float b = W2[(size_t)(2 * p + 1) * R_EMB + j];
        w2t[idx] = rne_bf16(a) | (rne_bf16(b) << 16);
    }
}

// 4 waves per block, one dst node per wave: 2048 blocks x 256 threads.
// acc = W1s[d] + sum_s W1s[s] (pre-scaled by dis[src]); h1s[d] = bf16(dis[d]*relu(dis[d]*acc + b1)).
// Edge loop unrolled x4 (4 independent loads in flight), dual accumulator sets.
__global__ void layer1_kernel(const u32* __restrict__ W1s, const float* __restrict__ b1,
                              const int* __restrict__ row_start, const int* __restrict__ sorted_src,
                              const float* __restrict__ dis, u32* __restrict__ h1s) {
    int d = blockIdx.x * 4 + (threadIdx.x >> 6);
    int t = threadIdx.x & 63;  // each lane owns 8 features
    float disd = dis[d];
    const uint4* base = (const uint4*)W1s;  // 64 uint4 per row

    uint4 wd = base[(d << 6) + t];
    float a0 = bf_lo(wd.x), a1 = bf_hi(wd.x), a2 = bf_lo(wd.y), a3 = bf_hi(wd.y);
    float a4 = bf_lo(wd.z), a5 = bf_hi(wd.z), a6 = bf_lo(wd.w), a7 = bf_hi(wd.w);
    float c0 = 0, c1 = 0, c2 = 0, c3 = 0, c4 = 0, c5 = 0, c6 = 0, c7 = 0;

    int beg = row_start[d], end = row_start[d + 1];
    int n = end - beg;
    int i = beg;
    int rem = n & 3;
    for (int r = 0; r < rem; r++) {
        int s = sorted_src[i++];
        uint4 v0 = base[(s << 6) + t];
        ACC8(a, v0)
    }
    for (; i < end; i += 4) {
        int s0 = sorted_src[i];
        int s1 = sorted_src[i + 1];
        int s2 = sorted_src[i + 2];
        int s3 = sorted_src[i + 3];
        uint4 v0 = base[(s0 << 6) + t];
        uint4 v1 = base[(s1 << 6) + t];
        uint4 v2 = base[(s2 << 6) + t];
        uint4 v3 = base[(s3 << 6) + t];
        ACC8(a, v0)
        ACC8(c, v1)
        ACC8(a, v2)
        ACC8(c, v3)
    }
    a0 += c0; a1 += c1; a2 += c2; a3 += c3;
    a4 += c4; a5 += c5; a6 += c6; a7 += c7;

    int f = t * 8;
    float4 bl = *(const float4*)(b1 + f);
    float4 bh = *(const float4*)(b1 + f + 4);
    float o0 = fmaxf(a0 * disd + bl.x, 0.0f) * disd;
    float o1 = fmaxf(a1 * disd + bl.y, 0.0f) * disd;
    float o2 = fmaxf(a2 * disd + bl.z, 0.0f) * disd;
    float o3 = fmaxf(a3 * disd + bl.w, 0.0f) * disd;
    float o4 = fmaxf(a4 * disd + bh.x, 0.0f) * disd;
    float o5 = fmaxf(a5 * disd + bh.y, 0.0f) * disd;
    float o6 = fmaxf(a6 * disd + bh.z, 0.0f) * disd;
    float o7 = fmaxf(a7 * disd + bh.w, 0.0f) * disd;
    uint4 o;
    o.x = rne_bf16(o0) | (rne_bf16(o1) << 16);
    o.y = rne_bf16(o2) | (rne_bf16(o3) << 16);
    o.z = rne_bf16(o4) | (rne_bf16(o5) << 16);
    o.w = rne_bf16(o6) | (rne_bf16(o7) << 16);
    ((uint4*)h1s)[(d << 6) + t] = o;
}

// 4 waves per block, one target per wave: 512 blocks x 256 threads.
// g[t] = dis[d]*(sum_s h1s[s] + h1s[d]), d = reg_id[t]; packed bf16 for MFMA.
__global__ void layer2_agg_kernel(const u32* __restrict__ h1s, const int* __restrict__ reg_id,
                                  const int* __restrict__ row_start, const int* __restrict__ sorted_src,
                                  const float* __restrict__ dis, u32* __restrict__ g_bf) {
    int tgt = blockIdx.x * 4 + (threadIdx.x >> 6);
    int d = reg_id[tgt];
    int t = threadIdx.x & 63;
    float disd = dis[d];
    const uint4* base = (const uint4*)h1s;

    uint4 wd = base[(d << 6) + t];
    float a0 = bf_lo(wd.x), a1 = bf_hi(wd.x), a2 = bf_lo(wd.y), a3 = bf_hi(wd.y);
    float a4 = bf_lo(wd.z), a5 = bf_hi(wd.z), a6 = bf_lo(wd.w), a7 = bf_hi(wd.w);
    float c0 = 0, c1 = 0, c2 = 0, c3 = 0, c4 = 0, c5 = 0, c6 = 0, c7 = 0;

    int beg = row_start[d], end = row_start[d + 1];
    int n = end - beg;
    int i = beg;
    int rem = n & 3;
    for (int r = 0; r < rem; r++) {
        int s = sorted_src[i++];
        uint4 v0 = base[(s << 6) + t];
        ACC8(a, v0)
    }
    for (; i < end; i += 4) {
        int s0 = sorted_src[i];
        int s1 = sorted_src[i + 1];
        int s2 = sorted_src[i + 2];
        int s3 = sorted_src[i + 3];
        uint4 v0 = base[(s0 << 6) + t];
        uint4 v1 = base[(s1 << 6) + t];
        uint4 v2 = base[(s2 << 6) + t];
        uint4 v3 = base[(s3 << 6) + t];
        ACC8(a, v0)
        ACC8(c, v1)
        ACC8(a, v2)
        ACC8(c, v3)
    }
    a0 += c0; a1 += c1; a2 += c2; a3 += c3;
    a4 += c4; a5 += c5; a6 += c6; a7 += c7;

    uint4 o;
    o.x = rne_bf16(a0 * disd) | (rne_bf16(a1 * disd) << 16);
    o.y = rne_bf16(a2 * disd) | (rne_bf16(a3 * disd) << 16);
    o.z = rne_bf16(a4 * disd) | (rne_bf16(a5 * disd) << 16);
    o.w = rne_bf16(a6 * disd) | (rne_bf16(a7 * disd) << 16);
    ((uint4*)g_bf)[(tgt << 6) + t] = o;
}

// out = g @ W2 + b2 via MFMA.  M=2048, K=512, N=128.
// One wave per 16x16 output tile: 1024 waves = 256 blocks x 4 waves.
// D: col = lane&15, row = (lane>>4)*4 + reg  [m89-verified].
__global__ void gemm_out_mfma(const u32* __restrict__ g_bf, const u32* __restrict__ w2t_bf,
                              const float* __restrict__ b2, float* __restrict__ out) {
    int w = blockIdx.x * 4 + (threadIdx.x >> 6);   // 0..1023
    int lane = threadIdx.x & 63;
    int tm = w >> 3;        // 0..127
    int tn = w & 7;         // 0..7
    int r15 = lane & 15;
    int kb4 = (lane >> 4) << 2;   // u32 offset of this lane's k-block

    const uint4* arow = (const uint4*)(g_bf + ((tm * 16 + r15) << 8) + kb4);
    const uint4* brow = (const uint4*)(w2t_bf + ((tn * 16 + r15) << 8) + kb4);
    frag_cd acc = {0.0f, 0.0f, 0.0f, 0.0f};
#pragma unroll
    for (int kk = 0; kk < 16; kk++) {
        uint4 av = arow[kk * 4];   // +16 u32 per K-step of 32
        uint4 bv = brow[kk * 4];
        acc = __builtin_amdgcn_mfma_f32_16x16x32_bf16(*(frag_ab*)&av, *(frag_ab*)&bv, acc, 0, 0, 0);
    }
    int col = tn * 16 + r15;
    int row0 = tm * 16 + ((lane >> 4) << 2);
    float bias = b2[col];
#pragma unroll
    for (int r = 0; r < 4; r++)
        out[(size_t)(row0 + r) * R_EMB + col] = acc[r] + bias;
}

extern "C" void kernel_launch(void* const* d_in, const int* in_sizes, int n_in,
                              void* d_out, int out_size, void* d_ws, size_t ws_size,
                              hipStream_t stream) {
    const int* reg_id = (const int*)d_in[0];
    const int* edge = (const int*)d_in[1];
    const float* W1 = (const float*)d_in[2];
    const float* b1 = (const float*)d_in[3];
    const float* W2 = (const float*)d_in[4];
    const float* b2 = (const float*)d_in[5];
    float* out = (float*)d_out;

    char* ws = (char*)d_ws;
    int* deg = (int*)(ws + OFF_DEG);
    int* row_start = (int*)(ws + OFF_ROWSTART);
    int* cursor = (int*)(ws + OFF_CURSOR);
    float* dis = (float*)(ws + OFF_DIS);
    int* sorted_src = (int*)(ws + OFF_SORTED);
    u32* W1s = (u32*)(ws + OFF_W1S);
    u32* h1s = (u32*)(ws + OFF_H1S);
    u32* w2t = (u32*)(ws + OFF_W2T);
    u32* g_bf = (u32*)(ws + OFF_G);

    hipMemsetAsync(deg, 0, N_NODE * sizeof(int), stream);

    hist_kernel<<<N_EDGE / 256, 256, 0, stream>>>(edge, deg);
    scan_kernel<<<1, 1024, 0, stream>>>(deg, row_start, cursor, dis);
    prep_kernel<<<1024 + 8192 + 128, 256, 0, stream>>>(edge, cursor, sorted_src,
                                                       W1, dis, W1s, W2, w2t);
    layer1_kernel<<<N_NODE / 4, 256, 0, stream>>>(W1s, b1, row_start, sorted_src, dis, h1s);
    layer2_agg_kernel<<<N_REG / 4, 256, 0, stream>>>(h1s, reg_id, row_start, sorted_src, dis, g_bf);
    gemm_out_mfma<<<256, 256, 0, stream>>>(g_bf, w2t, b2, out);
}